// Round 9
// baseline (6016.295 us; speedup 1.0000x reference)
//
#include <hip/hip_runtime.h>
#include <math.h>

#define NUSR 50000
#define NITM 30000
#define NN (NUSR + NITM)
#define DD 64
#define BATCH 1024
#define E_PV 2000000
#define E_CART 600000
#define E_BUY 600000
#define E_ALL 3000000
#define TOT_E (E_PV + E_CART + E_BUY + E_ALL)

__constant__ int c_eoff[5] = {0, E_PV, E_PV + E_CART, E_PV + E_CART + E_BUY, TOT_E};

// ---------------------------------------------------------------- CSR build
__global__ void hist_kernel(const int* __restrict__ r0, const int* __restrict__ r1,
                            const int* __restrict__ r2, const int* __restrict__ r3,
                            int* __restrict__ cnt) {
    int i = blockIdx.x * 256 + threadIdx.x;
    if (i >= TOT_E) return;
    int g = (i < c_eoff[1]) ? 0 : (i < c_eoff[2]) ? 1 : (i < c_eoff[3]) ? 2 : 3;
    const int* rp = (g == 0) ? r0 : (g == 1) ? r1 : (g == 2) ? r2 : r3;
    int r = rp[i - c_eoff[g]];
    atomicAdd(&cnt[(size_t)g * NN + r], 1);
}

__global__ void scan_kernel(const int* __restrict__ counts, int* __restrict__ ptrs,
                            int* __restrict__ cursor) {
    int g = blockIdx.x;                       // one block per adjacency
    const int* cnt = counts + (size_t)g * NN;
    int* p = ptrs + (size_t)g * (NN + 1);
    int* cur = cursor + (size_t)g * NN;
    int t = threadIdx.x;                      // 0..1023
    const int CH = (NN + 1023) / 1024;
    int beg = t * CH;
    int end = beg + CH; if (end > NN) end = NN;
    int s = 0;
    for (int i = beg; i < end; ++i) s += cnt[i];
    __shared__ int lds[1024];
    lds[t] = s;
    __syncthreads();
    for (int off = 1; off < 1024; off <<= 1) {
        int v = 0;
        if (t >= off) v = lds[t - off];
        __syncthreads();
        lds[t] += v;
        __syncthreads();
    }
    int run = lds[t] - s;                     // exclusive prefix
    for (int i = beg; i < end; ++i) {
        p[i] = run; cur[i] = run; run += cnt[i];
    }
    if (t == 1023) p[NN] = lds[1023];
}

__global__ void scatter_kernel(const int* __restrict__ r0, const int* __restrict__ r1,
                               const int* __restrict__ r2, const int* __restrict__ r3,
                               const int* __restrict__ c0, const int* __restrict__ c1,
                               const int* __restrict__ c2, const int* __restrict__ c3,
                               const float* __restrict__ v0, const float* __restrict__ v1,
                               const float* __restrict__ v2, const float* __restrict__ v3,
                               int* __restrict__ cur, int* __restrict__ ocol,
                               float* __restrict__ oval) {
    int i = blockIdx.x * 256 + threadIdx.x;
    if (i >= TOT_E) return;
    int g = (i < c_eoff[1]) ? 0 : (i < c_eoff[2]) ? 1 : (i < c_eoff[3]) ? 2 : 3;
    int li = i - c_eoff[g];
    const int* rp = (g == 0) ? r0 : (g == 1) ? r1 : (g == 2) ? r2 : r3;
    const int* cp = (g == 0) ? c0 : (g == 1) ? c1 : (g == 2) ? c2 : c3;
    const float* vp = (g == 0) ? v0 : (g == 1) ? v1 : (g == 2) ? v2 : v3;
    int r = rp[li];
    int pth = atomicAdd(&cur[(size_t)g * NN + r], 1);   // graph-local slot
    ocol[c_eoff[g] + pth] = cp[li];
    oval[c_eoff[g] + pth] = vp[li];
}

// ---------------------------------------------------------------- propagate
__global__ void init_kernel(const float* __restrict__ eu, const float* __restrict__ ei,
                            const float* __restrict__ beh, float* __restrict__ x,
                            float* __restrict__ acc) {
    int idx = blockIdx.x * 256 + threadIdx.x;
    if (idx >= NN * DD) return;
    int d = idx & 63;
    float b = beh ? beh[d] : 0.0f;
    float v = (idx < NUSR * DD ? eu[idx] : ei[idx - NUSR * DD]) + b;
    x[idx] = v;
    acc[idx] = v;
}

__global__ __launch_bounds__(512) void spmm_kernel(const int* __restrict__ ptrs,
        const int* __restrict__ cols, const float* __restrict__ vals,
        const float* __restrict__ xin, float* __restrict__ xout, float* __restrict__ acc) {
    int row = (blockIdx.x << 3) + (threadIdx.x >> 6);   // wave per row, 8 rows/block
    int lane = threadIdx.x & 63;
    if (row >= NN) return;
    int j = ptrs[row], end = ptrs[row + 1];
    float sum = 0.0f;
    for (; j + 4 <= end; j += 4) {
        int cc0 = cols[j + 0], cc1 = cols[j + 1], cc2 = cols[j + 2], cc3 = cols[j + 3];
        float w0 = vals[j + 0], w1 = vals[j + 1], w2 = vals[j + 2], w3 = vals[j + 3];
        float x0 = xin[(size_t)cc0 * DD + lane];
        float x1 = xin[(size_t)cc1 * DD + lane];
        float x2 = xin[(size_t)cc2 * DD + lane];
        float x3 = xin[(size_t)cc3 * DD + lane];
        sum = fmaf(w0, x0, sum); sum = fmaf(w1, x1, sum);
        sum = fmaf(w2, x2, sum); sum = fmaf(w3, x3, sum);
    }
    for (; j < end; ++j) sum = fmaf(vals[j], xin[(size_t)cols[j] * DD + lane], sum);
    int o = row * DD + lane;
    xout[o] = sum;
    acc[o] += sum;
}

__global__ void extract_kernel(const float* __restrict__ acc, const int* __restrict__ busers,
                               float* __restrict__ i_all, float* __restrict__ u_all_b) {
    int idx = blockIdx.x * 256 + threadIdx.x;
    if (idx < NITM * DD) {
        i_all[idx] = acc[NUSR * DD + idx] * 0.25f;
    } else if (idx < NITM * DD + BATCH * DD) {
        int k = idx - NITM * DD;
        int b = k >> 6, d = k & 63;
        u_all_b[k] = acc[(size_t)busers[b] * DD + d] * 0.25f;
    }
}

// ---------------------------------------------------------------- gates
__global__ __launch_bounds__(256) void gate_item_kernel(const float* __restrict__ i_all,
        const float* __restrict__ acc, const float* __restrict__ W,
        const float* __restrict__ bias, float* __restrict__ ib) {
    __shared__ float Wl[DD * 65];
    int tid = threadIdx.x;
    {
        int r = tid & 63, kq = tid >> 6;
        #pragma unroll
        for (int i = 0; i < 4; ++i) {
            float4 w4 = *(const float4*)&W[r * DD + kq * 16 + i * 4];
            Wl[r * 65 + kq * 16 + i * 4 + 0] = w4.x;
            Wl[r * 65 + kq * 16 + i * 4 + 1] = w4.y;
            Wl[r * 65 + kq * 16 + i * 4 + 2] = w4.z;
            Wl[r * 65 + kq * 16 + i * 4 + 3] = w4.w;
        }
    }
    __syncthreads();
    int lane = tid & 63;
    int row = (blockIdx.x << 2) + (tid >> 6);
    if (row >= NITM) return;
    float a = i_all[row * DD + lane];
    float bv = acc[(size_t)(NUSR + row) * DD + lane] * 0.25f;
    float t = bias[lane];
    #pragma unroll
    for (int k = 0; k < DD; ++k) t = fmaf(__shfl(a, k, 64), Wl[lane * 65 + k], t);
    float g = 1.0f / (1.0f + expf(-t));
    ib[row * DD + lane] = g * a + (1.0f - g) * bv;
}

__global__ __launch_bounds__(256) void gate_user_kernel(const float* __restrict__ u_all_b,
        const float* __restrict__ acc, const int* __restrict__ busers,
        const float* __restrict__ W, const float* __restrict__ bias,
        const float* __restrict__ wvec, float* __restrict__ ubs) {
    __shared__ float Wl[DD * 65];
    int tid = threadIdx.x;
    {
        int r = tid & 63, kq = tid >> 6;
        #pragma unroll
        for (int i = 0; i < 4; ++i) {
            float4 w4 = *(const float4*)&W[r * DD + kq * 16 + i * 4];
            Wl[r * 65 + kq * 16 + i * 4 + 0] = w4.x;
            Wl[r * 65 + kq * 16 + i * 4 + 1] = w4.y;
            Wl[r * 65 + kq * 16 + i * 4 + 2] = w4.z;
            Wl[r * 65 + kq * 16 + i * 4 + 3] = w4.w;
        }
    }
    __syncthreads();
    int lane = tid & 63;
    int row = (blockIdx.x << 2) + (tid >> 6);
    if (row >= BATCH) return;
    float a = u_all_b[row * DD + lane];
    float bv = acc[(size_t)busers[row] * DD + lane] * 0.25f;
    float t = bias[lane];
    #pragma unroll
    for (int k = 0; k < DD; ++k) t = fmaf(__shfl(a, k, 64), Wl[lane * 65 + k], t);
    float g = 1.0f / (1.0f + expf(-t));
    float ub = g * a + (1.0f - g) * bv;
    float s = ub * ub;
    #pragma unroll
    for (int off = 32; off; off >>= 1) s += __shfl_xor(s, off, 64);
    float nrm = sqrtf(s) + 1e-12f;
    ubs[row * DD + lane] = ub / nrm * wvec[lane];
}

// ---------------------------------------------------------------- likelihood GEMM
#define GBM 64
#define GBN 128
__global__ __launch_bounds__(256) void gemm_kernel(const float* __restrict__ A,
        const float* __restrict__ Bm, float* __restrict__ C) {
    __shared__ __align__(16) float As[DD][GBM + 4];
    __shared__ __align__(16) float Bs[DD][GBN + 4];
    int tid = threadIdx.x;
    int bm = blockIdx.y * GBM;
    int bn = blockIdx.x * GBN;
    {   // A tile: 64 rows x 64 k
        int m = tid & 63, kq = tid >> 6;
        #pragma unroll
        for (int i = 0; i < 4; ++i) {
            float4 v = *(const float4*)&A[(size_t)(bm + m) * DD + kq * 16 + i * 4];
            As[kq * 16 + i * 4 + 0][m] = v.x;
            As[kq * 16 + i * 4 + 1][m] = v.y;
            As[kq * 16 + i * 4 + 2][m] = v.z;
            As[kq * 16 + i * 4 + 3][m] = v.w;
        }
    }
    {   // B tile: 128 rows x 64 k
        int n = tid >> 1, kh = (tid & 1) * 32;
        int grow = bn + n;
        #pragma unroll
        for (int i = 0; i < 8; ++i) {
            float4 v = make_float4(0.f, 0.f, 0.f, 0.f);
            if (grow < NITM) v = *(const float4*)&Bm[(size_t)grow * DD + kh + i * 4];
            Bs[kh + i * 4 + 0][n] = v.x;
            Bs[kh + i * 4 + 1][n] = v.y;
            Bs[kh + i * 4 + 2][n] = v.z;
            Bs[kh + i * 4 + 3][n] = v.w;
        }
    }
    __syncthreads();
    int ty = tid >> 4, tx = tid & 15;
    float accr[4][8];
    #pragma unroll
    for (int r = 0; r < 4; ++r)
        #pragma unroll
        for (int c = 0; c < 8; ++c) accr[r][c] = 0.0f;
    #pragma unroll
    for (int k = 0; k < DD; ++k) {
        float a4[4], b8[8];
        *(float4*)a4 = *(const float4*)&As[k][ty * 4];
        *(float4*)b8 = *(const float4*)&Bs[k][tx * 8];
        *(float4*)(b8 + 4) = *(const float4*)&Bs[k][tx * 8 + 4];
        #pragma unroll
        for (int r = 0; r < 4; ++r)
            #pragma unroll
            for (int c = 0; c < 8; ++c) accr[r][c] = fmaf(a4[r], b8[c], accr[r][c]);
    }
    int jbase = bn + tx * 8;
    bool fast = (jbase + 8 <= NITM - 1);
    #pragma unroll
    for (int r = 0; r < 4; ++r) {
        size_t off = (size_t)(bm + ty * 4 + r) * NITM + jbase;
        if (fast) {
            float4 o0, o1;
            o0.x = fmaxf(accr[r][0], 0.f); o0.y = fmaxf(accr[r][1], 0.f);
            o0.z = fmaxf(accr[r][2], 0.f); o0.w = fmaxf(accr[r][3], 0.f);
            o1.x = fmaxf(accr[r][4], 0.f); o1.y = fmaxf(accr[r][5], 0.f);
            o1.z = fmaxf(accr[r][6], 0.f); o1.w = fmaxf(accr[r][7], 0.f);
            *(float4*)(C + off) = o0;
            *(float4*)(C + off + 4) = o1;
        } else {
            for (int c = 0; c < 8; ++c) {
                int j = jbase + c;
                if (j < NITM) {
                    float v = fmaxf(accr[r][c], 0.f);
                    if (j == NITM - 1) v = 0.f;
                    C[off + c] = v;
                }
            }
        }
    }
}

// ---------------------------------------------------------------- launch
extern "C" void kernel_launch(void* const* d_in, const int* in_sizes, int n_in,
                              void* d_out, int out_size, void* d_ws, size_t ws_size,
                              hipStream_t stream) {
    const float* emb_user = (const float*)d_in[0];
    const float* emb_item = (const float*)d_in[1];
    const float* beh[3] = {(const float*)d_in[2], (const float*)d_in[3], (const float*)d_in[4]};
    const int* g_rows[4]; const int* g_cols[4]; const float* g_vals[4];
    g_rows[0] = (const int*)d_in[5];  g_cols[0] = (const int*)d_in[6];  g_vals[0] = (const float*)d_in[7];
    g_rows[1] = (const int*)d_in[8];  g_cols[1] = (const int*)d_in[9];  g_vals[1] = (const float*)d_in[10];
    g_rows[2] = (const int*)d_in[11]; g_cols[2] = (const int*)d_in[12]; g_vals[2] = (const float*)d_in[13];
    g_rows[3] = (const int*)d_in[14]; g_cols[3] = (const int*)d_in[15]; g_vals[3] = (const float*)d_in[16];
    const float* guW[3] = {(const float*)d_in[17], (const float*)d_in[21], (const float*)d_in[25]};
    const float* gub[3] = {(const float*)d_in[18], (const float*)d_in[22], (const float*)d_in[26]};
    const float* giW[3] = {(const float*)d_in[19], (const float*)d_in[23], (const float*)d_in[27]};
    const float* gib[3] = {(const float*)d_in[20], (const float*)d_in[24], (const float*)d_in[28]};
    const float* wvec[3] = {(const float*)d_in[29], (const float*)d_in[30], (const float*)d_in[31]};
    const int* busers = (const int*)d_in[32];

    char* p = (char*)d_ws;
    auto alloc = [&](size_t bytes) {
        char* r = p;
        p += (bytes + 255) & ~(size_t)255;
        return r;
    };
    int*   counts  = (int*)alloc((size_t)4 * NN * sizeof(int));
    int*   ptrs    = (int*)alloc((size_t)4 * (NN + 1) * sizeof(int));
    int*   cursor  = (int*)alloc((size_t)4 * NN * sizeof(int));
    int*   csr_col = (int*)alloc((size_t)TOT_E * sizeof(int));
    float* csr_val = (float*)alloc((size_t)TOT_E * sizeof(float));
    float* ping    = (float*)alloc((size_t)NN * DD * sizeof(float));
    float* pong    = (float*)alloc((size_t)NN * DD * sizeof(float));
    float* accb    = (float*)alloc((size_t)NN * DD * sizeof(float));
    float* i_all   = (float*)alloc((size_t)NITM * DD * sizeof(float));
    float* u_all_b = (float*)alloc((size_t)BATCH * DD * sizeof(float));
    float* ibuf    = (float*)alloc((size_t)NITM * DD * sizeof(float));
    float* ubuf    = (float*)alloc((size_t)BATCH * DD * sizeof(float));
    if ((size_t)(p - (char*)d_ws) > ws_size) return;   // workspace too small

    const size_t EOFF[4] = {0, E_PV, E_PV + E_CART, E_PV + E_CART + E_BUY};

    hipMemsetAsync(counts, 0, (size_t)4 * NN * sizeof(int), stream);
    hist_kernel<<<(TOT_E + 255) / 256, 256, 0, stream>>>(
        g_rows[0], g_rows[1], g_rows[2], g_rows[3], counts);
    scan_kernel<<<4, 1024, 0, stream>>>(counts, ptrs, cursor);
    scatter_kernel<<<(TOT_E + 255) / 256, 256, 0, stream>>>(
        g_rows[0], g_rows[1], g_rows[2], g_rows[3],
        g_cols[0], g_cols[1], g_cols[2], g_cols[3],
        g_vals[0], g_vals[1], g_vals[2], g_vals[3],
        cursor, csr_col, csr_val);

    // propagate: 'all' (storage id 3) first, then pv(0), cart(1), buy(2)
    const int order[4] = {3, 0, 1, 2};
    for (int oi = 0; oi < 4; ++oi) {
        int g = order[oi];
        const float* bvec = (g == 3) ? nullptr : beh[g];
        init_kernel<<<(NN * DD + 255) / 256, 256, 0, stream>>>(emb_user, emb_item, bvec, ping, accb);
        float* xi = ping; float* xo = pong;
        for (int l = 0; l < 3; ++l) {
            spmm_kernel<<<(NN + 7) / 8, 512, 0, stream>>>(ptrs + (size_t)g * (NN + 1),
                csr_col + EOFF[g], csr_val + EOFF[g], xi, xo, accb);
            float* t = xi; xi = xo; xo = t;
        }
        if (g == 3) {
            extract_kernel<<<((NITM + BATCH) * DD + 255) / 256, 256, 0, stream>>>(
                accb, busers, i_all, u_all_b);
        } else {
            gate_item_kernel<<<(NITM + 3) / 4, 256, 0, stream>>>(i_all, accb, giW[g], gib[g], ibuf);
            gate_user_kernel<<<(BATCH + 3) / 4, 256, 0, stream>>>(u_all_b, accb, busers,
                guW[g], gub[g], wvec[g], ubuf);
            gemm_kernel<<<dim3((NITM + GBN - 1) / GBN, BATCH / GBM), 256, 0, stream>>>(
                ubuf, ibuf, (float*)d_out + (size_t)g * BATCH * NITM);
        }
    }
}

// Round 10
// 2422.192 us; speedup vs baseline: 2.4838x; 2.4838x over previous
//
#include <hip/hip_runtime.h>
#include <math.h>

#define NUSR 50000
#define NITM 30000
#define NN (NUSR + NITM)
#define DD 64
#define BATCH 1024
#define E_PV 2000000
#define E_CART 600000
#define E_BUY 600000
#define E_ALL 3000000
#define TOT_E (E_PV + E_CART + E_BUY + E_ALL)

__constant__ int c_eoff[5] = {0, E_PV, E_PV + E_CART, E_PV + E_CART + E_BUY, TOT_E};

// ---------------------------------------------------------------- CSR build
__global__ void hist_kernel(const int* __restrict__ r0, const int* __restrict__ r1,
                            const int* __restrict__ r2, const int* __restrict__ r3,
                            int* __restrict__ cnt) {
    int i = blockIdx.x * 256 + threadIdx.x;
    if (i >= TOT_E) return;
    int g = (i < c_eoff[1]) ? 0 : (i < c_eoff[2]) ? 1 : (i < c_eoff[3]) ? 2 : 3;
    const int* rp = (g == 0) ? r0 : (g == 1) ? r1 : (g == 2) ? r2 : r3;
    int r = rp[i - c_eoff[g]];
    atomicAdd(&cnt[(size_t)g * NN + r], 1);
}

__global__ void scan_kernel(const int* __restrict__ counts, int* __restrict__ ptrs,
                            int* __restrict__ cursor) {
    int g = blockIdx.x;                       // one block per adjacency
    const int* cnt = counts + (size_t)g * NN;
    int* p = ptrs + (size_t)g * (NN + 1);
    int* cur = cursor + (size_t)g * NN;
    int t = threadIdx.x;                      // 0..1023
    const int CH = (NN + 1023) / 1024;
    int beg = t * CH;
    int end = beg + CH; if (end > NN) end = NN;
    int s = 0;
    for (int i = beg; i < end; ++i) s += cnt[i];
    __shared__ int lds[1024];
    lds[t] = s;
    __syncthreads();
    for (int off = 1; off < 1024; off <<= 1) {
        int v = 0;
        if (t >= off) v = lds[t - off];
        __syncthreads();
        lds[t] += v;
        __syncthreads();
    }
    int run = lds[t] - s;                     // exclusive prefix
    for (int i = beg; i < end; ++i) {
        p[i] = run; cur[i] = run; run += cnt[i];
    }
    if (t == 1023) p[NN] = lds[1023];
}

__global__ void scatter_kernel(const int* __restrict__ r0, const int* __restrict__ r1,
                               const int* __restrict__ r2, const int* __restrict__ r3,
                               const int* __restrict__ c0, const int* __restrict__ c1,
                               const int* __restrict__ c2, const int* __restrict__ c3,
                               const float* __restrict__ v0, const float* __restrict__ v1,
                               const float* __restrict__ v2, const float* __restrict__ v3,
                               int* __restrict__ cur, int* __restrict__ ocol,
                               float* __restrict__ oval) {
    int i = blockIdx.x * 256 + threadIdx.x;
    if (i >= TOT_E) return;
    int g = (i < c_eoff[1]) ? 0 : (i < c_eoff[2]) ? 1 : (i < c_eoff[3]) ? 2 : 3;
    int li = i - c_eoff[g];
    const int* rp = (g == 0) ? r0 : (g == 1) ? r1 : (g == 2) ? r2 : r3;
    const int* cp = (g == 0) ? c0 : (g == 1) ? c1 : (g == 2) ? c2 : c3;
    const float* vp = (g == 0) ? v0 : (g == 1) ? v1 : (g == 2) ? v2 : v3;
    int r = rp[li];
    int pth = atomicAdd(&cur[(size_t)g * NN + r], 1);   // graph-local slot
    ocol[c_eoff[g] + pth] = cp[li];
    oval[c_eoff[g] + pth] = vp[li];
}

// ---------------------------------------------------------------- propagate
__global__ void init_kernel(const float* __restrict__ eu, const float* __restrict__ ei,
                            const float* __restrict__ beh, float* __restrict__ x,
                            float* __restrict__ acc) {
    int idx = blockIdx.x * 256 + threadIdx.x;
    if (idx >= NN * DD) return;
    int d = idx & 63;
    float b = beh ? beh[d] : 0.0f;
    float v = (idx < NUSR * DD ? eu[idx] : ei[idx - NUSR * DD]) + b;
    x[idx] = v;
    acc[idx] = v;
}

__global__ __launch_bounds__(512) void spmm_kernel(const int* __restrict__ ptrs,
        const int* __restrict__ cols, const float* __restrict__ vals,
        const float* __restrict__ xin, float* __restrict__ xout, float* __restrict__ acc) {
    int row = (blockIdx.x << 3) + (threadIdx.x >> 6);   // wave per row, 8 rows/block
    int lane = threadIdx.x & 63;
    if (row >= NN) return;
    int j = ptrs[row], end = ptrs[row + 1];
    float sum = 0.0f;
    for (; j + 4 <= end; j += 4) {
        int cc0 = cols[j + 0], cc1 = cols[j + 1], cc2 = cols[j + 2], cc3 = cols[j + 3];
        float w0 = vals[j + 0], w1 = vals[j + 1], w2 = vals[j + 2], w3 = vals[j + 3];
        float x0 = xin[(size_t)cc0 * DD + lane];
        float x1 = xin[(size_t)cc1 * DD + lane];
        float x2 = xin[(size_t)cc2 * DD + lane];
        float x3 = xin[(size_t)cc3 * DD + lane];
        sum = fmaf(w0, x0, sum); sum = fmaf(w1, x1, sum);
        sum = fmaf(w2, x2, sum); sum = fmaf(w3, x3, sum);
    }
    for (; j < end; ++j) sum = fmaf(vals[j], xin[(size_t)cols[j] * DD + lane], sum);
    int o = row * DD + lane;
    xout[o] = sum;
    acc[o] += sum;
}

__global__ void extract_kernel(const float* __restrict__ acc, const int* __restrict__ busers,
                               float* __restrict__ i_all, float* __restrict__ u_all_b) {
    int idx = blockIdx.x * 256 + threadIdx.x;
    if (idx < NITM * DD) {
        i_all[idx] = acc[NUSR * DD + idx] * 0.25f;
    } else if (idx < NITM * DD + BATCH * DD) {
        int k = idx - NITM * DD;
        int b = k >> 6, d = k & 63;
        u_all_b[k] = acc[(size_t)busers[b] * DD + d] * 0.25f;
    }
}

// ---------------------------------------------------------------- gates
__global__ __launch_bounds__(256) void gate_item_kernel(const float* __restrict__ i_all,
        const float* __restrict__ acc, const float* __restrict__ W,
        const float* __restrict__ bias, float* __restrict__ ib) {
    __shared__ float Wl[DD * 65];
    int tid = threadIdx.x;
    {
        int r = tid & 63, kq = tid >> 6;
        #pragma unroll
        for (int i = 0; i < 4; ++i) {
            float4 w4 = *(const float4*)&W[r * DD + kq * 16 + i * 4];
            Wl[r * 65 + kq * 16 + i * 4 + 0] = w4.x;
            Wl[r * 65 + kq * 16 + i * 4 + 1] = w4.y;
            Wl[r * 65 + kq * 16 + i * 4 + 2] = w4.z;
            Wl[r * 65 + kq * 16 + i * 4 + 3] = w4.w;
        }
    }
    __syncthreads();
    int lane = tid & 63;
    int row = (blockIdx.x << 2) + (tid >> 6);
    if (row >= NITM) return;
    float a = i_all[row * DD + lane];
    float bv = acc[(size_t)(NUSR + row) * DD + lane] * 0.25f;
    float t = bias[lane];
    #pragma unroll
    for (int k = 0; k < DD; ++k) t = fmaf(__shfl(a, k, 64), Wl[lane * 65 + k], t);
    float g = 1.0f / (1.0f + expf(-t));
    ib[row * DD + lane] = g * a + (1.0f - g) * bv;
}

__global__ __launch_bounds__(256) void gate_user_kernel(const float* __restrict__ u_all_b,
        const float* __restrict__ acc, const int* __restrict__ busers,
        const float* __restrict__ W, const float* __restrict__ bias,
        const float* __restrict__ wvec, float* __restrict__ ubs) {
    __shared__ float Wl[DD * 65];
    int tid = threadIdx.x;
    {
        int r = tid & 63, kq = tid >> 6;
        #pragma unroll
        for (int i = 0; i < 4; ++i) {
            float4 w4 = *(const float4*)&W[r * DD + kq * 16 + i * 4];
            Wl[r * 65 + kq * 16 + i * 4 + 0] = w4.x;
            Wl[r * 65 + kq * 16 + i * 4 + 1] = w4.y;
            Wl[r * 65 + kq * 16 + i * 4 + 2] = w4.z;
            Wl[r * 65 + kq * 16 + i * 4 + 3] = w4.w;
        }
    }
    __syncthreads();
    int lane = tid & 63;
    int row = (blockIdx.x << 2) + (tid >> 6);
    if (row >= BATCH) return;
    float a = u_all_b[row * DD + lane];
    float bv = acc[(size_t)busers[row] * DD + lane] * 0.25f;
    float t = bias[lane];
    #pragma unroll
    for (int k = 0; k < DD; ++k) t = fmaf(__shfl(a, k, 64), Wl[lane * 65 + k], t);
    float g = 1.0f / (1.0f + expf(-t));
    float ub = g * a + (1.0f - g) * bv;
    float s = ub * ub;
    #pragma unroll
    for (int off = 32; off; off >>= 1) s += __shfl_xor(s, off, 64);
    float nrm = sqrtf(s) + 1e-12f;
    ubs[row * DD + lane] = ub / nrm * wvec[lane];
}

// ---------------------------------------------------------------- likelihood GEMM
// R9 fix: VGPR=256 + 2.94 GB/dispatch diagnosed as scratch-spill from
// address-taken local float arrays + full k=64 unroll. Rewritten with named
// float4 temporaries (no address-taken storage), #pragma unroll 4 on k, and
// B-fragment split tx*4 / 64+tx*4 (LDS 2-way aliasing = free, was 4-way).
// Accumulation order per output unchanged -> bitwise-identical results.
#define GBM 64
#define GBN 128
__global__ __launch_bounds__(256) void gemm_kernel(const float* __restrict__ A,
        const float* __restrict__ Bm, float* __restrict__ C) {
    __shared__ __align__(16) float As[DD][GBM + 4];
    __shared__ __align__(16) float Bs[DD][GBN + 4];
    int tid = threadIdx.x;
    int bm = blockIdx.y * GBM;
    int bn = blockIdx.x * GBN;
    {   // A tile: 64 rows x 64 k
        int m = tid & 63, kq = tid >> 6;
        #pragma unroll
        for (int i = 0; i < 4; ++i) {
            float4 v = *(const float4*)&A[(size_t)(bm + m) * DD + kq * 16 + i * 4];
            As[kq * 16 + i * 4 + 0][m] = v.x;
            As[kq * 16 + i * 4 + 1][m] = v.y;
            As[kq * 16 + i * 4 + 2][m] = v.z;
            As[kq * 16 + i * 4 + 3][m] = v.w;
        }
    }
    {   // B tile: 128 rows x 64 k
        int n = tid >> 1, kh = (tid & 1) * 32;
        int grow = bn + n;
        #pragma unroll
        for (int i = 0; i < 8; ++i) {
            float4 v = make_float4(0.f, 0.f, 0.f, 0.f);
            if (grow < NITM) v = *(const float4*)&Bm[(size_t)grow * DD + kh + i * 4];
            Bs[kh + i * 4 + 0][n] = v.x;
            Bs[kh + i * 4 + 1][n] = v.y;
            Bs[kh + i * 4 + 2][n] = v.z;
            Bs[kh + i * 4 + 3][n] = v.w;
        }
    }
    __syncthreads();
    int ty = tid >> 4, tx = tid & 15;       // rows ty*4..+3, cols tx*4 and 64+tx*4
    float4 acc0[4], acc1[4];
    #pragma unroll
    for (int r = 0; r < 4; ++r) {
        acc0[r] = make_float4(0.f, 0.f, 0.f, 0.f);
        acc1[r] = make_float4(0.f, 0.f, 0.f, 0.f);
    }
    #pragma unroll 4
    for (int k = 0; k < DD; ++k) {
        float4 av = *(const float4*)&As[k][ty * 4];
        float4 b0 = *(const float4*)&Bs[k][tx * 4];
        float4 b1 = *(const float4*)&Bs[k][64 + tx * 4];
        #pragma unroll
        for (int r = 0; r < 4; ++r) {
            float ar = (r == 0) ? av.x : (r == 1) ? av.y : (r == 2) ? av.z : av.w;
            acc0[r].x = fmaf(ar, b0.x, acc0[r].x);
            acc0[r].y = fmaf(ar, b0.y, acc0[r].y);
            acc0[r].z = fmaf(ar, b0.z, acc0[r].z);
            acc0[r].w = fmaf(ar, b0.w, acc0[r].w);
            acc1[r].x = fmaf(ar, b1.x, acc1[r].x);
            acc1[r].y = fmaf(ar, b1.y, acc1[r].y);
            acc1[r].z = fmaf(ar, b1.z, acc1[r].z);
            acc1[r].w = fmaf(ar, b1.w, acc1[r].w);
        }
    }
    int j0 = bn + tx * 4;                   // first column group
    int j1 = bn + 64 + tx * 4;              // second column group
    #pragma unroll
    for (int r = 0; r < 4; ++r) {
        size_t rowoff = (size_t)(bm + ty * 4 + r) * NITM;
        float4 o;
        // group 0
        o.x = fmaxf(acc0[r].x, 0.f); o.y = fmaxf(acc0[r].y, 0.f);
        o.z = fmaxf(acc0[r].z, 0.f); o.w = fmaxf(acc0[r].w, 0.f);
        if (j0 + 4 <= NITM - 1) {
            *(float4*)(C + rowoff + j0) = o;
        } else {
            float oc[4] = {o.x, o.y, o.z, o.w};
            #pragma unroll
            for (int c = 0; c < 4; ++c) {
                int j = j0 + c;
                if (j < NITM) C[rowoff + j] = (j == NITM - 1) ? 0.f : oc[c];
            }
        }
        // group 1
        o.x = fmaxf(acc1[r].x, 0.f); o.y = fmaxf(acc1[r].y, 0.f);
        o.z = fmaxf(acc1[r].z, 0.f); o.w = fmaxf(acc1[r].w, 0.f);
        if (j1 + 4 <= NITM - 1) {
            *(float4*)(C + rowoff + j1) = o;
        } else {
            float oc[4] = {o.x, o.y, o.z, o.w};
            #pragma unroll
            for (int c = 0; c < 4; ++c) {
                int j = j1 + c;
                if (j < NITM) C[rowoff + j] = (j == NITM - 1) ? 0.f : oc[c];
            }
        }
    }
}

// ---------------------------------------------------------------- launch
extern "C" void kernel_launch(void* const* d_in, const int* in_sizes, int n_in,
                              void* d_out, int out_size, void* d_ws, size_t ws_size,
                              hipStream_t stream) {
    const float* emb_user = (const float*)d_in[0];
    const float* emb_item = (const float*)d_in[1];
    const float* beh[3] = {(const float*)d_in[2], (const float*)d_in[3], (const float*)d_in[4]};
    const int* g_rows[4]; const int* g_cols[4]; const float* g_vals[4];
    g_rows[0] = (const int*)d_in[5];  g_cols[0] = (const int*)d_in[6];  g_vals[0] = (const float*)d_in[7];
    g_rows[1] = (const int*)d_in[8];  g_cols[1] = (const int*)d_in[9];  g_vals[1] = (const float*)d_in[10];
    g_rows[2] = (const int*)d_in[11]; g_cols[2] = (const int*)d_in[12]; g_vals[2] = (const float*)d_in[13];
    g_rows[3] = (const int*)d_in[14]; g_cols[3] = (const int*)d_in[15]; g_vals[3] = (const float*)d_in[16];
    const float* guW[3] = {(const float*)d_in[17], (const float*)d_in[21], (const float*)d_in[25]};
    const float* gub[3] = {(const float*)d_in[18], (const float*)d_in[22], (const float*)d_in[26]};
    const float* giW[3] = {(const float*)d_in[19], (const float*)d_in[23], (const float*)d_in[27]};
    const float* gib[3] = {(const float*)d_in[20], (const float*)d_in[24], (const float*)d_in[28]};
    const float* wvec[3] = {(const float*)d_in[29], (const float*)d_in[30], (const float*)d_in[31]};
    const int* busers = (const int*)d_in[32];

    char* p = (char*)d_ws;
    auto alloc = [&](size_t bytes) {
        char* r = p;
        p += (bytes + 255) & ~(size_t)255;
        return r;
    };
    int*   counts  = (int*)alloc((size_t)4 * NN * sizeof(int));
    int*   ptrs    = (int*)alloc((size_t)4 * (NN + 1) * sizeof(int));
    int*   cursor  = (int*)alloc((size_t)4 * NN * sizeof(int));
    int*   csr_col = (int*)alloc((size_t)TOT_E * sizeof(int));
    float* csr_val = (float*)alloc((size_t)TOT_E * sizeof(float));
    float* ping    = (float*)alloc((size_t)NN * DD * sizeof(float));
    float* pong    = (float*)alloc((size_t)NN * DD * sizeof(float));
    float* accb    = (float*)alloc((size_t)NN * DD * sizeof(float));
    float* i_all   = (float*)alloc((size_t)NITM * DD * sizeof(float));
    float* u_all_b = (float*)alloc((size_t)BATCH * DD * sizeof(float));
    float* ibuf    = (float*)alloc((size_t)NITM * DD * sizeof(float));
    float* ubuf    = (float*)alloc((size_t)BATCH * DD * sizeof(float));
    if ((size_t)(p - (char*)d_ws) > ws_size) return;   // workspace too small

    const size_t EOFF[4] = {0, E_PV, E_PV + E_CART, E_PV + E_CART + E_BUY};

    hipMemsetAsync(counts, 0, (size_t)4 * NN * sizeof(int), stream);
    hist_kernel<<<(TOT_E + 255) / 256, 256, 0, stream>>>(
        g_rows[0], g_rows[1], g_rows[2], g_rows[3], counts);
    scan_kernel<<<4, 1024, 0, stream>>>(counts, ptrs, cursor);
    scatter_kernel<<<(TOT_E + 255) / 256, 256, 0, stream>>>(
        g_rows[0], g_rows[1], g_rows[2], g_rows[3],
        g_cols[0], g_cols[1], g_cols[2], g_cols[3],
        g_vals[0], g_vals[1], g_vals[2], g_vals[3],
        cursor, csr_col, csr_val);

    // propagate: 'all' (storage id 3) first, then pv(0), cart(1), buy(2)
    const int order[4] = {3, 0, 1, 2};
    for (int oi = 0; oi < 4; ++oi) {
        int g = order[oi];
        const float* bvec = (g == 3) ? nullptr : beh[g];
        init_kernel<<<(NN * DD + 255) / 256, 256, 0, stream>>>(emb_user, emb_item, bvec, ping, accb);
        float* xi = ping; float* xo = pong;
        for (int l = 0; l < 3; ++l) {
            spmm_kernel<<<(NN + 7) / 8, 512, 0, stream>>>(ptrs + (size_t)g * (NN + 1),
                csr_col + EOFF[g], csr_val + EOFF[g], xi, xo, accb);
            float* t = xi; xi = xo; xo = t;
        }
        if (g == 3) {
            extract_kernel<<<((NITM + BATCH) * DD + 255) / 256, 256, 0, stream>>>(
                accb, busers, i_all, u_all_b);
        } else {
            gate_item_kernel<<<(NITM + 3) / 4, 256, 0, stream>>>(i_all, accb, giW[g], gib[g], ibuf);
            gate_user_kernel<<<(BATCH + 3) / 4, 256, 0, stream>>>(u_all_b, accb, busers,
                guW[g], gub[g], wvec[g], ubuf);
            gemm_kernel<<<dim3((NITM + GBN - 1) / GBN, BATCH / GBM), 256, 0, stream>>>(
                ubuf, ibuf, (float*)d_out + (size_t)g * BATCH * NITM);
        }
    }
}